// Round 2
// baseline (163.877 us; speedup 1.0000x reference)
//
#include <hip/hip_runtime.h>

// Problem constants (fixed by reference): B=16, H=W=1024.
#define NPIX (16u * 1024u * 1024u)    // 16,777,216 pixels
#define NOCTS (NPIX / 8u)             // 2,097,152 groups of 8 pixels
#define NBLOCKS 2048
#define NTHREADS 256
#define NITERS (NOCTS / (NBLOCKS * NTHREADS))  // = 4, exact (no remainder)

// Workspace layout: [0..3]: ticket counter (zeroed by memset each launch),
// [256..256+8192): per-block partials (2048 floats).
#define PARTIALS_OFF 256

// Fused single-pass reduction. Each iteration loads 8 pixels = 8 float4
// (4 pred + 2 char_gt + 2 aff_gt = 128 B/thread/iter), issued back-to-back
// for memory-level parallelism. Last block (ticketed) does the deterministic
// final sum in double and writes the scalar loss.
__global__ __launch_bounds__(NTHREADS) void ohem_fused_kernel(
    const float4* __restrict__ pred4,
    const float4* __restrict__ cgt4,
    const float4* __restrict__ agt4,
    unsigned* __restrict__ counter,
    float* __restrict__ partials,
    float* __restrict__ out) {
  const unsigned tid = blockIdx.x * NTHREADS + threadIdx.x;
  const unsigned stride = NBLOCKS * NTHREADS;

  float acc = 0.0f;
  #pragma unroll 2
  for (unsigned it = 0; it < NITERS; ++it) {
    const unsigned o = tid + it * stride;
    // 8 independent 16B loads, all issued before any use.
    const float4 p0 = pred4[4u * o + 0u];
    const float4 p1 = pred4[4u * o + 1u];
    const float4 p2 = pred4[4u * o + 2u];
    const float4 p3 = pred4[4u * o + 3u];
    const float4 c0 = cgt4[2u * o + 0u];
    const float4 c1 = cgt4[2u * o + 1u];
    const float4 a0 = agt4[2u * o + 0u];
    const float4 a1 = agt4[2u * o + 1u];
    float d;
    d = p0.x - c0.x; acc = fmaf(d, d, acc);
    d = p0.z - c0.y; acc = fmaf(d, d, acc);
    d = p1.x - c0.z; acc = fmaf(d, d, acc);
    d = p1.z - c0.w; acc = fmaf(d, d, acc);
    d = p2.x - c1.x; acc = fmaf(d, d, acc);
    d = p2.z - c1.y; acc = fmaf(d, d, acc);
    d = p3.x - c1.z; acc = fmaf(d, d, acc);
    d = p3.z - c1.w; acc = fmaf(d, d, acc);
    d = p0.y - a0.x; acc = fmaf(d, d, acc);
    d = p0.w - a0.y; acc = fmaf(d, d, acc);
    d = p1.y - a0.z; acc = fmaf(d, d, acc);
    d = p1.w - a0.w; acc = fmaf(d, d, acc);
    d = p2.y - a1.x; acc = fmaf(d, d, acc);
    d = p2.w - a1.y; acc = fmaf(d, d, acc);
    d = p3.y - a1.z; acc = fmaf(d, d, acc);
    d = p3.w - a1.w; acc = fmaf(d, d, acc);
  }

  // Wave-64 butterfly reduce.
  #pragma unroll
  for (int off = 32; off > 0; off >>= 1) acc += __shfl_down(acc, off, 64);

  __shared__ float smemf[NTHREADS / 64];
  __shared__ bool is_last;
  const int wave = threadIdx.x >> 6;
  if ((threadIdx.x & 63) == 0) smemf[wave] = acc;
  __syncthreads();

  if (threadIdx.x == 0) {
    float t = 0.0f;
    #pragma unroll
    for (int w = 0; w < NTHREADS / 64; ++w) t += smemf[w];
    // Release-store the partial (device scope: visible across XCD L2s),
    // then take a ticket. acq_rel RMW synchronizes with all prior releases.
    __hip_atomic_store(&partials[blockIdx.x], t, __ATOMIC_RELEASE,
                       __HIP_MEMORY_SCOPE_AGENT);
    unsigned ticket = __hip_atomic_fetch_add(counter, 1u, __ATOMIC_ACQ_REL,
                                             __HIP_MEMORY_SCOPE_AGENT);
    is_last = (ticket == NBLOCKS - 1u);
  }
  __syncthreads();

  if (is_last) {
    // Deterministic final reduce: fixed order, double accumulation.
    double dacc = 0.0;
    for (int i = threadIdx.x; i < NBLOCKS; i += NTHREADS) {
      float v = __hip_atomic_load(&partials[i], __ATOMIC_RELAXED,
                                  __HIP_MEMORY_SCOPE_AGENT);
      dacc += (double)v;
    }
    #pragma unroll
    for (int off = 32; off > 0; off >>= 1) dacc += __shfl_down(dacc, off, 64);

    __shared__ double smemd[NTHREADS / 64];
    if ((threadIdx.x & 63) == 0) smemd[wave] = dacc;
    __syncthreads();
    if (threadIdx.x == 0) {
      double t = 0.0;
      #pragma unroll
      for (int w = 0; w < NTHREADS / 64; ++w) t += smemd[w];
      // loss = sum_sq_char/N + sum_sq_aff/N = total_sum_sq / N
      out[0] = (float)(t / (double)NPIX);
    }
  }
}

extern "C" void kernel_launch(void* const* d_in, const int* in_sizes, int n_in,
                              void* d_out, int out_size, void* d_ws, size_t ws_size,
                              hipStream_t stream) {
  const float4* pred4 = (const float4*)d_in[0];  // [B,H,W,2] fp32
  const float4* cgt4 = (const float4*)d_in[1];   // [B,H,W] fp32
  const float4* agt4 = (const float4*)d_in[2];   // [B,H,W] fp32
  float* out = (float*)d_out;
  unsigned* counter = (unsigned*)d_ws;
  float* partials = (float*)((char*)d_ws + PARTIALS_OFF);

  // Zero the ticket counter every launch (graph-capture-safe async memset).
  hipMemsetAsync(counter, 0, sizeof(unsigned), stream);
  ohem_fused_kernel<<<NBLOCKS, NTHREADS, 0, stream>>>(pred4, cgt4, agt4,
                                                      counter, partials, out);
}

// Round 3
// 51.338 us; speedup vs baseline: 3.1921x; 3.1921x over previous
//
#include <hip/hip_runtime.h>

// Problem constants (fixed by reference): B=16, H=W=1024.
#define NPIX (16u * 1024u * 1024u)   // B*H*W = 16,777,216 pixels
#define NQUADS (NPIX / 4u)           // 4,194,304 quads (4 pixels each)
#define NBLOCKS 2048
#define NTHREADS 256
#define STRIDE (NBLOCKS * NTHREADS)  // 524,288 threads
#define NITERS (NQUADS / STRIDE)     // = 8, exact

// Stage 1: per-block partial sum of squared errors over both channels.
// Lane-contiguous addressing (lane i -> base + 16B*i within each load):
// pred4[2q], pred4[2q+1] with q=tid -> two interleaved fully-dense 1KB/wave
// streams; cgt4[q]/agt4[q] perfectly contiguous. Unrolled x2 so 8 float4
// loads (2 grid-stride points, 8MB apart) are in flight per wave.
__global__ __launch_bounds__(NTHREADS) void ohem_partial_kernel(
    const float4* __restrict__ pred4,
    const float4* __restrict__ cgt4,
    const float4* __restrict__ agt4,
    float* __restrict__ partials) {
  const unsigned tid = blockIdx.x * NTHREADS + threadIdx.x;

  float acc = 0.0f;
  #pragma unroll
  for (unsigned it = 0; it < NITERS / 2; ++it) {
    const unsigned qa = tid + (2u * it) * STRIDE;
    const unsigned qb = tid + (2u * it + 1u) * STRIDE;
    // 8 independent coalesced 16B loads, issued before any use.
    const float4 pa0 = pred4[2u * qa];
    const float4 pa1 = pred4[2u * qa + 1u];
    const float4 ca  = cgt4[qa];
    const float4 aa  = agt4[qa];
    const float4 pb0 = pred4[2u * qb];
    const float4 pb1 = pred4[2u * qb + 1u];
    const float4 cb  = cgt4[qb];
    const float4 ab  = agt4[qb];
    float d;
    d = pa0.x - ca.x; acc = fmaf(d, d, acc);
    d = pa0.z - ca.y; acc = fmaf(d, d, acc);
    d = pa1.x - ca.z; acc = fmaf(d, d, acc);
    d = pa1.z - ca.w; acc = fmaf(d, d, acc);
    d = pa0.y - aa.x; acc = fmaf(d, d, acc);
    d = pa0.w - aa.y; acc = fmaf(d, d, acc);
    d = pa1.y - aa.z; acc = fmaf(d, d, acc);
    d = pa1.w - aa.w; acc = fmaf(d, d, acc);
    d = pb0.x - cb.x; acc = fmaf(d, d, acc);
    d = pb0.z - cb.y; acc = fmaf(d, d, acc);
    d = pb1.x - cb.z; acc = fmaf(d, d, acc);
    d = pb1.z - cb.w; acc = fmaf(d, d, acc);
    d = pb0.y - ab.x; acc = fmaf(d, d, acc);
    d = pb0.w - ab.y; acc = fmaf(d, d, acc);
    d = pb1.y - ab.z; acc = fmaf(d, d, acc);
    d = pb1.w - ab.w; acc = fmaf(d, d, acc);
  }

  // Wave-64 butterfly reduce.
  #pragma unroll
  for (int off = 32; off > 0; off >>= 1) acc += __shfl_down(acc, off, 64);

  __shared__ float smem[NTHREADS / 64];
  const int wave = threadIdx.x >> 6;
  if ((threadIdx.x & 63) == 0) smem[wave] = acc;
  __syncthreads();
  if (threadIdx.x == 0) {
    float t = 0.0f;
    #pragma unroll
    for (int w = 0; w < NTHREADS / 64; ++w) t += smem[w];
    partials[blockIdx.x] = t;
  }
}

// Stage 2: deterministic final reduce (one block), double accumulation.
__global__ __launch_bounds__(NTHREADS) void ohem_final_kernel(
    const float* __restrict__ partials, float* __restrict__ out) {
  double acc = 0.0;
  for (int i = threadIdx.x; i < NBLOCKS; i += NTHREADS) acc += (double)partials[i];

  #pragma unroll
  for (int off = 32; off > 0; off >>= 1) acc += __shfl_down(acc, off, 64);

  __shared__ double smem[NTHREADS / 64];
  const int wave = threadIdx.x >> 6;
  if ((threadIdx.x & 63) == 0) smem[wave] = acc;
  __syncthreads();
  if (threadIdx.x == 0) {
    double t = 0.0;
    #pragma unroll
    for (int w = 0; w < NTHREADS / 64; ++w) t += smem[w];
    // loss = sum_sq_char/N + sum_sq_aff/N = total_sum_sq / N
    out[0] = (float)(t / (double)NPIX);
  }
}

extern "C" void kernel_launch(void* const* d_in, const int* in_sizes, int n_in,
                              void* d_out, int out_size, void* d_ws, size_t ws_size,
                              hipStream_t stream) {
  const float4* pred4 = (const float4*)d_in[0];  // [B,H,W,2] fp32
  const float4* cgt4 = (const float4*)d_in[1];   // [B,H,W] fp32
  const float4* agt4 = (const float4*)d_in[2];   // [B,H,W] fp32
  float* out = (float*)d_out;
  float* partials = (float*)d_ws;  // NBLOCKS floats = 8 KB

  ohem_partial_kernel<<<NBLOCKS, NTHREADS, 0, stream>>>(pred4, cgt4, agt4, partials);
  ohem_final_kernel<<<1, NTHREADS, 0, stream>>>(partials, out);
}